// Round 11
// baseline (810.746 us; speedup 1.0000x reference)
//
#include <hip/hip_runtime.h>
#include <stdint.h>

// ParentGRU fused: 12x (65536x512)@(512x512) GEMMs + gates, via bf16 MFMA.
// R11: R10's BK=32 / 32KiB-LDS double-buffered 128x128 GEMM, but with RAW
// s_barrier + counted vmcnt(4) (T4) instead of __syncthreads. __syncthreads
// emits s_waitcnt vmcnt(0) (compiler) which force-drained R10's prefetch
// every step; raw barriers let tile kt+2 stay in flight across the barrier
// while occupancy stays ~4-5 blocks/CU (R9's lever).
//
// ws layout (bytes):
//   B1  @ 0           : 1536x1536 bf16   B2 @ 4,718,592 : 512x1536 bf16
//   hr  @ 6,291,456   : 65536x512 bf16 (h*sig(r))
//   pr1 @ 73,400,320  : 65536x512 bf16 (p*sig(r1))
//   Xb  @ 140,509,184 / Hb @ 207,618,048 / Pb @ 274,726,912 : bf16 inputs
//   attb@ 341,835,776 : 65536x512 bf16 (sigmoid att)  [ws >= 408,944,640: confirmed]

typedef unsigned short u16;
using bf16x8 = __attribute__((ext_vector_type(8))) __bf16;
using f32x4  = __attribute__((ext_vector_type(4))) float;

__device__ __forceinline__ u16 f2bf(float f) {
    __bf16 b = (__bf16)f;
    union { __bf16 b; u16 u; } v; v.b = b;
    return v.u;
}
__device__ __forceinline__ uint32_t f2bf2(float lo, float hi) {
    return (uint32_t)f2bf(lo) | ((uint32_t)f2bf(hi) << 16);
}
__device__ __forceinline__ float bf2f(u16 s) {
    union { uint32_t u; float f; } v; v.u = ((uint32_t)s) << 16;
    return v.f;
}
__device__ __forceinline__ void load_lds16(const void* g, void* l) {
    __builtin_amdgcn_global_load_lds(
        (const __attribute__((address_space(1))) uint32_t*)g,
        (__attribute__((address_space(3))) uint32_t*)l, 16, 0, 0);
}
__device__ __forceinline__ void fence_bar() {
    asm volatile("" ::: "memory");
    __builtin_amdgcn_s_barrier();          // raw barrier: NO implicit vmcnt drain
    asm volatile("" ::: "memory");
}

// ---------------- weight packing ----------------
__global__ void prep_weights(
    const float* __restrict__ wa, const float* __restrict__ ua, const float* __restrict__ pa,
    const float* __restrict__ wrg, const float* __restrict__ ur, const float* __restrict__ pr,
    const float* __restrict__ wr1, const float* __restrict__ ur1, const float* __restrict__ pr1,
    const float* __restrict__ wcc, const float* __restrict__ uc, const float* __restrict__ pc,
    u16* __restrict__ B1, u16* __restrict__ B2)
{
    int idx = blockIdx.x * 256 + threadIdx.x;
    const int T1 = 1536 * 1536;
    if (idx < T1) {
        int n = idx / 1536, k = idx - n * 1536;
        int g = n >> 9, nn = n & 511;
        int o = k >> 9, kk = k & 511;
        const float* s;
        if (g == 0)      s = (o == 0) ? wa  : (o == 1) ? ua  : pa;
        else if (g == 1) s = (o == 0) ? wrg : (o == 1) ? ur  : pr;
        else             s = (o == 0) ? wr1 : (o == 1) ? ur1 : pr1;
        B1[idx] = f2bf(s[nn * 512 + kk]);
    } else {
        int j = idx - T1;
        if (j < 512 * 1536) {
            int n = j / 1536, k = j - n * 1536;
            int o = k >> 9, kk = k & 511;
            const float* s = (o == 0) ? wcc : (o == 1) ? uc : pc;
            B2[j] = f2bf(s[n * 512 + kk]);
        }
    }
}

// ---------------- input cast: X,H,P fp32 -> bf16 ----------------
__global__ void cast_inputs(const float* __restrict__ X, const float* __restrict__ H,
                            const float* __restrict__ P,
                            u16* __restrict__ Xb, u16* __restrict__ Hb, u16* __restrict__ Pb)
{
    const long long MAT8 = (65536LL * 512) / 8;
    for (long long t = (long long)blockIdx.x * 256 + threadIdx.x;
         t < 3 * MAT8; t += (long long)gridDim.x * 256) {
        int m = (int)(t >> 22);
        long long e = (t & (MAT8 - 1)) * 8;
        const float* s = (m == 0) ? X : (m == 1) ? H : P;
        u16* d = (m == 0) ? Xb : (m == 1) ? Hb : Pb;
        f32x4 a = *(const f32x4*)(s + e);
        f32x4 b = *(const f32x4*)(s + e + 4);
        uint4 q;
        q.x = f2bf2(a.x, a.y); q.y = f2bf2(a.z, a.w);
        q.z = f2bf2(b.x, b.y); q.w = f2bf2(b.z, b.w);
        *(uint4*)(d + e) = q;
    }
}

// =============== 128x128 BK=32 dbuf GEMM, raw-bar + counted vmcnt ===============
// MODE 1: A=[Xb|Hb|Pb] (K=1536) @ B1^T, N=1536; sigmoid epilogue.
// MODE 2: A=[Xb|hr|pr1] @ B2^T, N=512; tanh + final combine epilogue.
template<int MODE>
__global__ __launch_bounds__(256, 4)
void g128(const u16* __restrict__ A0, const u16* __restrict__ A1s, const u16* __restrict__ A2s,
          const u16* __restrict__ Bw,
          const float* __restrict__ bias0, const float* __restrict__ bias1,
          const float* __restrict__ bias2,
          const u16* __restrict__ HbP, const u16* __restrict__ PbP,
          u16* __restrict__ attb, u16* __restrict__ hrw, u16* __restrict__ pr1w,
          float* __restrict__ outp)
{
    __shared__ u16 Ab[2][128 * 32];   // 2 x 8 KiB
    __shared__ u16 Bb[2][128 * 32];   // 2 x 8 KiB -> 32 KiB total

    const int tid  = threadIdx.x;
    const int lane = tid & 63;
    const int w    = tid >> 6;        // 4 waves
    const int wr   = w >> 1;          // 0..1 (M 64-half)
    const int wc   = w & 1;           // 0..1 (N 64-half)

    int panel, ntl;
    const int xcd = blockIdx.x & 7;
    const int idx = blockIdx.x >> 3;
    if (MODE == 1) { panel = xcd * 64 + idx / 12;   ntl = idx % 12; }
    else           { panel = xcd * 64 + (idx >> 2); ntl = idx & 3;  }
    const int m0 = panel * 128;
    const int n0 = ntl * 128;

    // ---- staging geometry (BK=32, 64B rows, 4x16B groups per row) ----
    // phys grp holds logical grp ^ ((row>>1)&3); LDS dest linear (tid*8 u16).
    const int srow = tid >> 2;                       // 0..63 (+64 on call 2)
    const int sgrp = tid & 3;
    const int sg2  = (sgrp ^ ((srow >> 1) & 3)) * 8; // logical col-group (u16)
    const int ofsA = srow * 512  + sg2;
    const int ofsB = srow * 1536 + sg2;
    const u16* const bA0 = A0  + (size_t)m0 * 512;
    const u16* const bA1 = A1s + (size_t)m0 * 512;
    const u16* const bA2 = A2s + (size_t)m0 * 512;
    const u16* const bB  = Bw  + (size_t)n0 * 1536;
    const int ldst = tid * 8;                        // u16 units

    auto stageA = [&](int kt, int nb) {
        const u16* src = (kt < 16) ? bA0 : (kt < 32) ? bA1 : bA2;
        const u16* g = src + (kt & 15) * 32 + ofsA;
        u16* lb = &Ab[nb][ldst];
        load_lds16(g,            lb);
        load_lds16(g + 64 * 512, lb + 2048);
    };
    auto stageB = [&](int kt, int nb) {
        const u16* g = bB + kt * 32 + ofsB;
        u16* lb = &Bb[nb][ldst];
        load_lds16(g,             lb);
        load_lds16(g + 64 * 1536, lb + 2048);
    };

    f32x4 acc[4][4];
    const f32x4 vz = {0.0f, 0.0f, 0.0f, 0.0f};
#pragma unroll
    for (int i = 0; i < 4; ++i)
#pragma unroll
        for (int j = 0; j < 4; ++j) acc[i][j] = vz;

    // ---- fragment read geometry ----
    const int fr  = lane & 15;
    const int cg  = (((lane >> 4) ^ ((fr >> 1) & 3))) * 8;   // swizzled col (u16)
    const int aOff = (wr * 64 + fr) * 32 + cg;               // + fm*512
    const int bOff = (wc * 64 + fr) * 32 + cg;               // + fn*512

    auto compute = [&](int cb) {
        bf16x8 af[4], bfr[4];
#pragma unroll
        for (int fm = 0; fm < 4; ++fm)
            af[fm] = *(const bf16x8*)&Ab[cb][aOff + fm * 512];
#pragma unroll
        for (int fn = 0; fn < 4; ++fn)
            bfr[fn] = *(const bf16x8*)&Bb[cb][bOff + fn * 512];
#pragma unroll
        for (int fm = 0; fm < 4; ++fm)
#pragma unroll
            for (int fn = 0; fn < 4; ++fn)
                acc[fm][fn] = __builtin_amdgcn_mfma_f32_16x16x32_bf16(
                    af[fm], bfr[fn], acc[fm][fn], 0, 0, 0);
    };

    // ---- pipelined loop: raw barriers, counted vmcnt (never 0 mid-loop) ----
    // prologue: tiles 0 and 1 in flight (4 loads each, per thread)
    stageA(0, 0); stageB(0, 0);
    stageA(1, 1); stageB(1, 1);
    asm volatile("s_waitcnt vmcnt(4)" ::: "memory");   // tile0 landed; tile1 in flight
    fence_bar();

    int buf = 0;
#pragma unroll 1
    for (int kt = 0; kt < 48; ++kt) {
        compute(buf);                                  // read tile kt from buf
        fence_bar();                                   // all waves done reading buf
        if (kt < 46) {
            stageA(kt + 2, buf); stageB(kt + 2, buf);  // refill freed buf
            // outstanding: kt+1 (4) + kt+2 (4); wait kt+1 landed, kt+2 in flight
            asm volatile("s_waitcnt vmcnt(4)" ::: "memory");
        } else if (kt == 46) {
            asm volatile("s_waitcnt vmcnt(0)" ::: "memory");   // last tile landed
        }
        fence_bar();
        buf ^= 1;
    }

    // ---- epilogue (32-bit offsets) ----
    const int rl = (lane >> 4) * 4;
    const int cl = lane & 15;
    const int rb0 = m0 + wr * 64 + rl;
    if (MODE == 1) {
        const int gate = ntl >> 2;   // 0:att 1:r 2:r1
        const float* bias = (gate == 0) ? bias0 : (gate == 1) ? bias1 : bias2;
        const int nnb = (ntl & 3) * 128 + wc * 64;
#pragma unroll
        for (int fm = 0; fm < 4; ++fm)
#pragma unroll
            for (int fn = 0; fn < 4; ++fn) {
                const int nn = nnb + fn * 16 + cl;
                const float b = bias[nn];
                int off = (rb0 + fm * 16) * 512 + nn;
#pragma unroll
                for (int j = 0; j < 4; ++j, off += 512) {
                    float v = acc[fm][fn][j] + b;
                    float s = 1.0f / (1.0f + __expf(-v));
                    if (gate == 0)      attb[off] = f2bf(s);
                    else if (gate == 1) hrw[off]  = f2bf(s * bf2f(HbP[off]));
                    else                pr1w[off] = f2bf(s * bf2f(PbP[off]));
                }
            }
    } else {
        const int nnb = n0 + wc * 64;
#pragma unroll
        for (int fm = 0; fm < 4; ++fm)
#pragma unroll
            for (int fn = 0; fn < 4; ++fn) {
                const int nn = nnb + fn * 16 + cl;
                const float b = bias0[nn];
                int off = (rb0 + fm * 16) * 512 + nn;
#pragma unroll
                for (int j = 0; j < 4; ++j, off += 512) {
                    float v = acc[fm][fn][j] + b;
                    float e = __expf(2.0f * v);
                    float ct = 1.0f - 2.0f / (e + 1.0f);   // tanh, inf-safe
                    float a = bf2f(attb[off]);
                    float h = bf2f(HbP[off]);
                    outp[off] = a * ct + (1.0f - a) * h;
                }
            }
    }
}

// =============== small-ws fallback: proven R2 128x128 kernels ===============
__global__ __launch_bounds__(256, 2)
void k1_small(const float* __restrict__ X, const float* __restrict__ H,
              const float* __restrict__ P, const u16* __restrict__ B1,
              const float* __restrict__ ba, const float* __restrict__ br,
              const float* __restrict__ br1,
              float* __restrict__ attf, u16* __restrict__ hrw, u16* __restrict__ pr1w)
{
    __shared__ u16 Ab[2][128 * 64];
    __shared__ u16 Bb[2][128 * 64];
    const int tid = threadIdx.x, lane = tid & 63, w = tid >> 6;
    const int wr = w >> 1, wc = w & 1;
    const int bid = blockIdx.x, xcd = bid & 7, idx = bid >> 3;
    const int panel = idx / 12, ntl = idx - panel * 12;
    const int m0 = (xcd * 64 + panel) * 128, n0 = ntl * 128;
    const int srow = w * 32 + (lane >> 3);
    const int scol = ((lane & 7) ^ (lane >> 3)) * 8;
    const int arow = tid >> 4, acol = (tid & 15) * 4;
    const int aswz = acol ^ ((arow & 7) << 3);
    f32x4 acc[4][4];
    const f32x4 vz = {0, 0, 0, 0};
#pragma unroll
    for (int i = 0; i < 4; ++i)
#pragma unroll
        for (int j = 0; j < 4; ++j) acc[i][j] = vz;
    f32x4 areg[8];
    auto issueA = [&](int kt) {
        const float* src = (kt < 8) ? X : (kt < 16) ? H : P;
        const float* base = src + (size_t)(m0 + arow) * 512 + (kt & 7) * 64 + acol;
#pragma unroll
        for (int rr = 0; rr < 8; ++rr)
            areg[rr] = *(const f32x4*)(base + (size_t)(rr * 16) * 512);
    };
    auto writeA = [&](int nb) {
#pragma unroll
        for (int rr = 0; rr < 8; ++rr) {
            uint2 q; q.x = f2bf2(areg[rr].x, areg[rr].y);
            q.y = f2bf2(areg[rr].z, areg[rr].w);
            *(uint2*)&Ab[nb][(arow + rr * 16) * 64 + aswz] = q;
        }
    };
    auto issueB = [&](int kt, int nb) {
        const u16* gb = B1 + (size_t)(n0 + srow) * 1536 + kt * 64 + scol;
        u16* lb = &Bb[nb][(w * 32) * 64];
#pragma unroll
        for (int c = 0; c < 4; ++c)
            load_lds16(gb + (size_t)c * 8 * 1536, lb + c * 8 * 64);
    };
    auto compute = [&](int cb) {
        const int rsw = (lane & 7) << 3, rb = lane & 15, hi8 = (lane >> 4) * 8;
#pragma unroll
        for (int ks = 0; ks < 2; ++ks) {
            bf16x8 af[4], bfr[4];
            const int col = (ks * 32 + hi8) ^ rsw;
#pragma unroll
            for (int fm = 0; fm < 4; ++fm)
                af[fm] = *(const bf16x8*)&Ab[cb][(wr * 64 + fm * 16 + rb) * 64 + col];
#pragma unroll
            for (int fn = 0; fn < 4; ++fn)
                bfr[fn] = *(const bf16x8*)&Bb[cb][(wc * 64 + fn * 16 + rb) * 64 + col];
#pragma unroll
            for (int fm = 0; fm < 4; ++fm)
#pragma unroll
                for (int fn = 0; fn < 4; ++fn)
                    acc[fm][fn] = __builtin_amdgcn_mfma_f32_16x16x32_bf16(
                        af[fm], bfr[fn], acc[fm][fn], 0, 0, 0);
        }
    };
    issueA(0); issueB(0, 0); writeA(0);
    __syncthreads();
    int cb = 0;
#pragma unroll 2
    for (int kt = 0; kt < 24; ++kt) {
        if (kt < 23) { issueA(kt + 1); issueB(kt + 1, cb ^ 1); }
        compute(cb);
        if (kt < 23) writeA(cb ^ 1);
        __syncthreads();
        cb ^= 1;
    }
    const int gate = ntl >> 2;
    const float* bias = (gate == 0) ? ba : (gate == 1) ? br : br1;
    const int nnb = (ntl & 3) * 128 + wc * 64;
    const int rl = (lane >> 4) * 4, cl = lane & 15;
#pragma unroll
    for (int fm = 0; fm < 4; ++fm)
#pragma unroll
        for (int fn = 0; fn < 4; ++fn) {
            const int nn = nnb + fn * 16 + cl;
            const float b = bias[nn];
#pragma unroll
            for (int j = 0; j < 4; ++j) {
                const int row = m0 + wr * 64 + fm * 16 + rl + j;
                const size_t off = (size_t)row * 512 + nn;
                float v = acc[fm][fn][j] + b;
                float s = 1.0f / (1.0f + __expf(-v));
                if (gate == 0)      attf[off] = s;
                else if (gate == 1) hrw[off]  = f2bf(s * H[off]);
                else                pr1w[off] = f2bf(s * P[off]);
            }
        }
}

__global__ __launch_bounds__(256, 2)
void k2_small(const float* __restrict__ X, const float* __restrict__ H,
              const u16* __restrict__ B2, const float* __restrict__ bc,
              const u16* __restrict__ hrw, const u16* __restrict__ pr1w,
              float* outp)
{
    __shared__ u16 Ab[2][128 * 64];
    __shared__ u16 Bb[2][128 * 64];
    const int tid = threadIdx.x, lane = tid & 63, w = tid >> 6;
    const int wr = w >> 1, wc = w & 1;
    const int bid = blockIdx.x, xcd = bid & 7, idx = bid >> 3;
    const int panel = idx >> 2, ntl = idx & 3;
    const int m0 = (xcd * 64 + panel) * 128, n0 = ntl * 128;
    const int srow = w * 32 + (lane >> 3);
    const int scol = ((lane & 7) ^ (lane >> 3)) * 8;
    const int arow = tid >> 4, acol = (tid & 15) * 4;
    const int aswz = acol ^ ((arow & 7) << 3);
    f32x4 acc[4][4];
    const f32x4 vz = {0, 0, 0, 0};
#pragma unroll
    for (int i = 0; i < 4; ++i)
#pragma unroll
        for (int j = 0; j < 4; ++j) acc[i][j] = vz;
    f32x4 areg[8];
    auto issueA = [&](int kt, int nb) {
        if (kt >= 8) {
            const u16* src = (kt < 16) ? hrw : pr1w;
            const u16* gb = src + (size_t)(m0 + srow) * 512 + (kt & 7) * 64 + scol;
            u16* lb = &Ab[nb][(w * 32) * 64];
#pragma unroll
            for (int c = 0; c < 4; ++c)
                load_lds16(gb + (size_t)c * 8 * 512, lb + c * 8 * 64);
        } else {
            const float* base = X + (size_t)(m0 + arow) * 512 + (kt & 7) * 64 + acol;
#pragma unroll
            for (int rr = 0; rr < 8; ++rr)
                areg[rr] = *(const f32x4*)(base + (size_t)(rr * 16) * 512);
        }
    };
    auto writeA = [&](int kt, int nb) {
        if (kt < 8) {
#pragma unroll
            for (int rr = 0; rr < 8; ++rr) {
                uint2 q; q.x = f2bf2(areg[rr].x, areg[rr].y);
                q.y = f2bf2(areg[rr].z, areg[rr].w);
                *(uint2*)&Ab[nb][(arow + rr * 16) * 64 + aswz] = q;
            }
        }
    };
    auto issueB = [&](int kt, int nb) {
        const u16* gb = B2 + (size_t)(n0 + srow) * 1536 + kt * 64 + scol;
        u16* lb = &Bb[nb][(w * 32) * 64];
#pragma unroll
        for (int c = 0; c < 4; ++c)
            load_lds16(gb + (size_t)c * 8 * 1536, lb + c * 8 * 64);
    };
    auto compute = [&](int cb) {
        const int rsw = (lane & 7) << 3, rb = lane & 15, hi8 = (lane >> 4) * 8;
#pragma unroll
        for (int ks = 0; ks < 2; ++ks) {
            bf16x8 af[4], bfr[4];
            const int col = (ks * 32 + hi8) ^ rsw;
#pragma unroll
            for (int fm = 0; fm < 4; ++fm)
                af[fm] = *(const bf16x8*)&Ab[cb][(wr * 64 + fm * 16 + rb) * 64 + col];
#pragma unroll
            for (int fn = 0; fn < 4; ++fn)
                bfr[fn] = *(const bf16x8*)&Bb[cb][(wc * 64 + fn * 16 + rb) * 64 + col];
#pragma unroll
            for (int fm = 0; fm < 4; ++fm)
#pragma unroll
                for (int fn = 0; fn < 4; ++fn)
                    acc[fm][fn] = __builtin_amdgcn_mfma_f32_16x16x32_bf16(
                        af[fm], bfr[fn], acc[fm][fn], 0, 0, 0);
        }
    };
    issueA(0, 0); issueB(0, 0); writeA(0, 0);
    __syncthreads();
    int cb = 0;
#pragma unroll 2
    for (int kt = 0; kt < 24; ++kt) {
        if (kt < 23) { issueA(kt + 1, cb ^ 1); issueB(kt + 1, cb ^ 1); }
        compute(cb);
        if (kt < 23) writeA(kt + 1, cb ^ 1);
        __syncthreads();
        cb ^= 1;
    }
    const int nnb = n0 + wc * 64;
    const int rl = (lane >> 4) * 4, cl = lane & 15;
#pragma unroll
    for (int fm = 0; fm < 4; ++fm)
#pragma unroll
        for (int fn = 0; fn < 4; ++fn) {
            const int nn = nnb + fn * 16 + cl;
            const float b = bc[nn];
#pragma unroll
            for (int j = 0; j < 4; ++j) {
                const int row = m0 + wr * 64 + fm * 16 + rl + j;
                const size_t off = (size_t)row * 512 + nn;
                float v = acc[fm][fn][j] + b;
                float e = __expf(2.0f * v);
                float ct = 1.0f - 2.0f / (e + 1.0f);
                float a = outp[off];
                outp[off] = a * ct + (1.0f - a) * H[off];
            }
        }
}

extern "C" void kernel_launch(void* const* d_in, const int* in_sizes, int n_in,
                              void* d_out, int out_size, void* d_ws, size_t ws_size,
                              hipStream_t stream)
{
    const float* X   = (const float*)d_in[0];
    const float* H   = (const float*)d_in[1];
    const float* P   = (const float*)d_in[2];
    const float* wa  = (const float*)d_in[3];
    const float* ba  = (const float*)d_in[4];
    const float* wrg = (const float*)d_in[5];
    const float* br  = (const float*)d_in[6];
    const float* wr1 = (const float*)d_in[7];
    const float* br1 = (const float*)d_in[8];
    const float* wcc = (const float*)d_in[9];
    const float* bc  = (const float*)d_in[10];
    const float* ua  = (const float*)d_in[11];
    const float* ur  = (const float*)d_in[12];
    const float* ur1 = (const float*)d_in[13];
    const float* uc  = (const float*)d_in[14];
    const float* pa  = (const float*)d_in[15];
    const float* pr  = (const float*)d_in[16];
    const float* pr1 = (const float*)d_in[17];
    const float* pc  = (const float*)d_in[18];

    char* ws = (char*)d_ws;
    u16* B1   = (u16*)(ws);
    u16* B2   = (u16*)(ws + (size_t)4718592);
    u16* hrp  = (u16*)(ws + (size_t)6291456);
    u16* pr1p = (u16*)(ws + (size_t)73400320);
    u16* Xb   = (u16*)(ws + (size_t)140509184);
    u16* Hb   = (u16*)(ws + (size_t)207618048);
    u16* Pb   = (u16*)(ws + (size_t)274726912);
    u16* attb = (u16*)(ws + (size_t)341835776);
    float* out = (float*)d_out;

    const bool big3 = ws_size >= (size_t)408944640ULL;

    prep_weights<<<12288, 256, 0, stream>>>(wa, ua, pa, wrg, ur, pr, wr1, ur1, pr1,
                                            wcc, uc, pc, B1, B2);
    if (big3) {
        cast_inputs<<<3072, 256, 0, stream>>>(X, H, P, Xb, Hb, Pb);
        g128<1><<<6144, 256, 0, stream>>>(Xb, Hb, Pb, B1, ba, br, br1,
                                          Hb, Pb, attb, hrp, pr1p, out);
        g128<2><<<2048, 256, 0, stream>>>(Xb, hrp, pr1p, B2, bc, nullptr, nullptr,
                                          Hb, nullptr, attb, nullptr, nullptr, out);
    } else {
        k1_small<<<6144, 256, 0, stream>>>(X, H, P, B1, ba, br, br1, out, hrp, pr1p);
        k2_small<<<2048, 256, 0, stream>>>(X, H, B2, bc, hrp, pr1p, out);
    }
}

// Round 13
// 688.753 us; speedup vs baseline: 1.1771x; 1.1771x over previous
//
#include <hip/hip_runtime.h>
#include <stdint.h>

// ParentGRU fused: 12x (65536x512)@(512x512) GEMMs + gates, via bf16 MFMA.
// R13: R12 with the MODE1 panel-mapping bug fixed (mg*128, not mg*64 — the
// 4 M-groups each own 128 panels; R12 overlapped groups and left panels
// 320-511 unwritten -> absmax 4.84). L2-fit XCD split otherwise unchanged:
// 4Mx2N for MODE1 (per-XCD B1 slice 2.36 MB < 4 MB L2).
//
// ws layout (bytes):
//   B1  @ 0           : 1536x1536 bf16   B2 @ 4,718,592 : 512x1536 bf16
//   hr  @ 6,291,456   : 65536x512 bf16 (h*sig(r))
//   pr1 @ 73,400,320  : 65536x512 bf16 (p*sig(r1))
//   Xb  @ 140,509,184 / Hb @ 207,618,048 / Pb @ 274,726,912 : bf16 inputs
//   attb@ 341,835,776 : 65536x512 bf16 (sigmoid att)  [ws >= 408,944,640: confirmed]

typedef unsigned short u16;
using bf16x8 = __attribute__((ext_vector_type(8))) __bf16;
using f32x4  = __attribute__((ext_vector_type(4))) float;

__device__ __forceinline__ u16 f2bf(float f) {
    __bf16 b = (__bf16)f;
    union { __bf16 b; u16 u; } v; v.b = b;
    return v.u;
}
__device__ __forceinline__ uint32_t f2bf2(float lo, float hi) {
    return (uint32_t)f2bf(lo) | ((uint32_t)f2bf(hi) << 16);
}
__device__ __forceinline__ float bf2f(u16 s) {
    union { uint32_t u; float f; } v; v.u = ((uint32_t)s) << 16;
    return v.f;
}
__device__ __forceinline__ void load_lds16(const void* g, void* l) {
    __builtin_amdgcn_global_load_lds(
        (const __attribute__((address_space(1))) uint32_t*)g,
        (__attribute__((address_space(3))) uint32_t*)l, 16, 0, 0);
}

// ---------------- weight packing ----------------
__global__ void prep_weights(
    const float* __restrict__ wa, const float* __restrict__ ua, const float* __restrict__ pa,
    const float* __restrict__ wrg, const float* __restrict__ ur, const float* __restrict__ pr,
    const float* __restrict__ wr1, const float* __restrict__ ur1, const float* __restrict__ pr1,
    const float* __restrict__ wcc, const float* __restrict__ uc, const float* __restrict__ pc,
    u16* __restrict__ B1, u16* __restrict__ B2)
{
    int idx = blockIdx.x * 256 + threadIdx.x;
    const int T1 = 1536 * 1536;
    if (idx < T1) {
        int n = idx / 1536, k = idx - n * 1536;
        int g = n >> 9, nn = n & 511;
        int o = k >> 9, kk = k & 511;
        const float* s;
        if (g == 0)      s = (o == 0) ? wa  : (o == 1) ? ua  : pa;
        else if (g == 1) s = (o == 0) ? wrg : (o == 1) ? ur  : pr;
        else             s = (o == 0) ? wr1 : (o == 1) ? ur1 : pr1;
        B1[idx] = f2bf(s[nn * 512 + kk]);
    } else {
        int j = idx - T1;
        if (j < 512 * 1536) {
            int n = j / 1536, k = j - n * 1536;
            int o = k >> 9, kk = k & 511;
            const float* s = (o == 0) ? wcc : (o == 1) ? uc : pc;
            B2[j] = f2bf(s[n * 512 + kk]);
        }
    }
}

// ---------------- input cast: X,H,P fp32 -> bf16 ----------------
__global__ void cast_inputs(const float* __restrict__ X, const float* __restrict__ H,
                            const float* __restrict__ P,
                            u16* __restrict__ Xb, u16* __restrict__ Hb, u16* __restrict__ Pb)
{
    const long long MAT8 = (65536LL * 512) / 8;
    for (long long t = (long long)blockIdx.x * 256 + threadIdx.x;
         t < 3 * MAT8; t += (long long)gridDim.x * 256) {
        int m = (int)(t >> 22);
        long long e = (t & (MAT8 - 1)) * 8;
        const float* s = (m == 0) ? X : (m == 1) ? H : P;
        u16* d = (m == 0) ? Xb : (m == 1) ? Hb : Pb;
        f32x4 a = *(const f32x4*)(s + e);
        f32x4 b = *(const f32x4*)(s + e + 4);
        uint4 q;
        q.x = f2bf2(a.x, a.y); q.y = f2bf2(a.z, a.w);
        q.z = f2bf2(b.x, b.y); q.w = f2bf2(b.z, b.w);
        *(uint4*)(d + e) = q;
    }
}

// =============== 128x128 single-buffer m97 GEMM (big path) ===============
// MODE 1: A=[Xb|Hb|Pb] (K=1536) @ B1^T, N=1536; sigmoid epilogue.
//         XCD split 4Mx2N: per-XCD B1 slice 2.36 MB -> L2-resident.
// MODE 2: A=[Xb|hr|pr1] @ B2^T, N=512; tanh + final combine epilogue.
template<int MODE>
__global__ __launch_bounds__(256, 4)
void g128(const u16* __restrict__ A0, const u16* __restrict__ A1s, const u16* __restrict__ A2s,
          const u16* __restrict__ Bw,
          const float* __restrict__ bias0, const float* __restrict__ bias1,
          const float* __restrict__ bias2,
          const u16* __restrict__ HbP, const u16* __restrict__ PbP,
          u16* __restrict__ attb, u16* __restrict__ hrw, u16* __restrict__ pr1w,
          float* __restrict__ outp)
{
    __shared__ u16 Ab[128 * 64];   // 16 KiB
    __shared__ u16 Bb[128 * 64];   // 16 KiB -> 32 KiB total

    const int tid  = threadIdx.x;
    const int lane = tid & 63;
    const int w    = tid >> 6;        // 4 waves
    const int wr   = w >> 1;          // 0..1 (M 64-half)
    const int wc   = w & 1;           // 0..1 (N 64-half)

    int panel, ntl;
    const int xcd = blockIdx.x & 7;
    const int idx = blockIdx.x >> 3;
    if (MODE == 1) {
        // 4 M-groups x 2 N-groups; each M-group owns 512/4 = 128 panels.
        const int mg = xcd >> 1, ng = xcd & 1;
        panel = mg * 128 + idx / 6;      // idx 0..767 -> idx/6 in [0,128)
        ntl   = ng * 6 + idx % 6;
    } else {
        panel = xcd * 64 + (idx >> 2);   // B2 slice 1.57 MB already L2-fit
        ntl   = idx & 3;
    }
    const int m0 = panel * 128;
    const int n0 = ntl * 128;

    // staging geometry (T2: LDS linear dest, global col pre-swizzled by row&7)
    const int srow = w * 32 + (lane >> 3);                // +c*8
    const int scol = ((lane & 7) ^ (lane >> 3)) * 8;
    const int ofsA = srow * 512  + scol;
    const int ofsB = srow * 1536 + scol;
    const u16* const bA0 = A0  + (size_t)m0 * 512;
    const u16* const bA1 = A1s + (size_t)m0 * 512;
    const u16* const bA2 = A2s + (size_t)m0 * 512;
    const u16* const bB  = Bw  + (size_t)n0 * 1536;

    auto issueA = [&](int kt) {
        const u16* src = (kt < 8) ? bA0 : (kt < 16) ? bA1 : bA2;
        const u16* g = src + (kt & 7) * 64 + ofsA;
        u16* lb = &Ab[(w * 32) * 64];
#pragma unroll
        for (int c = 0; c < 4; ++c)
            load_lds16(g + c * 8 * 512, lb + c * 8 * 64);
    };
    auto issueB = [&](int kt) {
        const u16* g = bB + kt * 64 + ofsB;
        u16* lb = &Bb[(w * 32) * 64];
#pragma unroll
        for (int c = 0; c < 4; ++c)
            load_lds16(g + c * 8 * 1536, lb + c * 8 * 64);
    };

    f32x4 acc[4][4];
    const f32x4 vz = {0.0f, 0.0f, 0.0f, 0.0f};
#pragma unroll
    for (int i = 0; i < 4; ++i)
#pragma unroll
        for (int j = 0; j < 4; ++j) acc[i][j] = vz;

    auto compute = [&]() {
        const int rsw = (lane & 7) << 3;
        const int rb  = lane & 15;
        const int hi8 = (lane >> 4) * 8;
#pragma unroll
        for (int ks = 0; ks < 2; ++ks) {
            bf16x8 af[4], bfr[4];
            const int col = (ks * 32 + hi8) ^ rsw;
#pragma unroll
            for (int fm = 0; fm < 4; ++fm)
                af[fm] = *(const bf16x8*)&Ab[(wr * 64 + fm * 16 + rb) * 64 + col];
#pragma unroll
            for (int fn = 0; fn < 4; ++fn)
                bfr[fn] = *(const bf16x8*)&Bb[(wc * 64 + fn * 16 + rb) * 64 + col];
#pragma unroll
            for (int fm = 0; fm < 4; ++fm)
#pragma unroll
                for (int fn = 0; fn < 4; ++fn)
                    acc[fm][fn] = __builtin_amdgcn_mfma_f32_16x16x32_bf16(
                        af[fm], bfr[fn], acc[fm][fn], 0, 0, 0);
        }
    };

    // m97 single-buffer loop: stage -> sync -> compute -> sync.
    // Cross-block TLP (~4 blocks/CU) hides the barrier drains.
#pragma unroll 1
    for (int kt = 0; kt < 24; ++kt) {
        issueA(kt); issueB(kt);
        __syncthreads();
        compute();
        __syncthreads();
    }

    // ---- epilogue (32-bit offsets) ----
    const int rl = (lane >> 4) * 4;
    const int cl = lane & 15;
    const int rb0 = m0 + wr * 64 + rl;
    if (MODE == 1) {
        const int gate = ntl >> 2;   // 0:att 1:r 2:r1
        const float* bias = (gate == 0) ? bias0 : (gate == 1) ? bias1 : bias2;
        const int nnb = (ntl & 3) * 128 + wc * 64;
#pragma unroll
        for (int fm = 0; fm < 4; ++fm)
#pragma unroll
            for (int fn = 0; fn < 4; ++fn) {
                const int nn = nnb + fn * 16 + cl;
                const float b = bias[nn];
                int off = (rb0 + fm * 16) * 512 + nn;
#pragma unroll
                for (int j = 0; j < 4; ++j, off += 512) {
                    float v = acc[fm][fn][j] + b;
                    float s = 1.0f / (1.0f + __expf(-v));
                    if (gate == 0)      attb[off] = f2bf(s);
                    else if (gate == 1) hrw[off]  = f2bf(s * bf2f(HbP[off]));
                    else                pr1w[off] = f2bf(s * bf2f(PbP[off]));
                }
            }
    } else {
        const int nnb = n0 + wc * 64;
#pragma unroll
        for (int fm = 0; fm < 4; ++fm)
#pragma unroll
            for (int fn = 0; fn < 4; ++fn) {
                const int nn = nnb + fn * 16 + cl;
                const float b = bias0[nn];
                int off = (rb0 + fm * 16) * 512 + nn;
#pragma unroll
                for (int j = 0; j < 4; ++j, off += 512) {
                    float v = acc[fm][fn][j] + b;
                    float e = __expf(2.0f * v);
                    float ct = 1.0f - 2.0f / (e + 1.0f);   // tanh, inf-safe
                    float a = bf2f(attb[off]);
                    float h = bf2f(HbP[off]);
                    outp[off] = a * ct + (1.0f - a) * h;
                }
            }
    }
}

// =============== small-ws fallback: proven R2 128x128 kernels ===============
__global__ __launch_bounds__(256, 2)
void k1_small(const float* __restrict__ X, const float* __restrict__ H,
              const float* __restrict__ P, const u16* __restrict__ B1,
              const float* __restrict__ ba, const float* __restrict__ br,
              const float* __restrict__ br1,
              float* __restrict__ attf, u16* __restrict__ hrw, u16* __restrict__ pr1w)
{
    __shared__ u16 Ab[2][128 * 64];
    __shared__ u16 Bb[2][128 * 64];
    const int tid = threadIdx.x, lane = tid & 63, w = tid >> 6;
    const int wr = w >> 1, wc = w & 1;
    const int bid = blockIdx.x, xcd = bid & 7, idx = bid >> 3;
    const int panel = idx / 12, ntl = idx - panel * 12;
    const int m0 = (xcd * 64 + panel) * 128, n0 = ntl * 128;
    const int srow = w * 32 + (lane >> 3);
    const int scol = ((lane & 7) ^ (lane >> 3)) * 8;
    const int arow = tid >> 4, acol = (tid & 15) * 4;
    const int aswz = acol ^ ((arow & 7) << 3);
    f32x4 acc[4][4];
    const f32x4 vz = {0, 0, 0, 0};
#pragma unroll
    for (int i = 0; i < 4; ++i)
#pragma unroll
        for (int j = 0; j < 4; ++j) acc[i][j] = vz;
    f32x4 areg[8];
    auto issueA = [&](int kt) {
        const float* src = (kt < 8) ? X : (kt < 16) ? H : P;
        const float* base = src + (size_t)(m0 + arow) * 512 + (kt & 7) * 64 + acol;
#pragma unroll
        for (int rr = 0; rr < 8; ++rr)
            areg[rr] = *(const f32x4*)(base + (size_t)(rr * 16) * 512);
    };
    auto writeA = [&](int nb) {
#pragma unroll
        for (int rr = 0; rr < 8; ++rr) {
            uint2 q; q.x = f2bf2(areg[rr].x, areg[rr].y);
            q.y = f2bf2(areg[rr].z, areg[rr].w);
            *(uint2*)&Ab[nb][(arow + rr * 16) * 64 + aswz] = q;
        }
    };
    auto issueB = [&](int kt, int nb) {
        const u16* gb = B1 + (size_t)(n0 + srow) * 1536 + kt * 64 + scol;
        u16* lb = &Bb[nb][(w * 32) * 64];
#pragma unroll
        for (int c = 0; c < 4; ++c)
            load_lds16(gb + (size_t)c * 8 * 1536, lb + c * 8 * 64);
    };
    auto compute = [&](int cb) {
        const int rsw = (lane & 7) << 3, rb = lane & 15, hi8 = (lane >> 4) * 8;
#pragma unroll
        for (int ks = 0; ks < 2; ++ks) {
            bf16x8 af[4], bfr[4];
            const int col = (ks * 32 + hi8) ^ rsw;
#pragma unroll
            for (int fm = 0; fm < 4; ++fm)
                af[fm] = *(const bf16x8*)&Ab[cb][(wr * 64 + fm * 16 + rb) * 64 + col];
#pragma unroll
            for (int fn = 0; fn < 4; ++fn)
                bfr[fn] = *(const bf16x8*)&Bb[cb][(wc * 64 + fn * 16 + rb) * 64 + col];
#pragma unroll
            for (int fm = 0; fm < 4; ++fm)
#pragma unroll
                for (int fn = 0; fn < 4; ++fn)
                    acc[fm][fn] = __builtin_amdgcn_mfma_f32_16x16x32_bf16(
                        af[fm], bfr[fn], acc[fm][fn], 0, 0, 0);
        }
    };
    issueA(0); issueB(0, 0); writeA(0);
    __syncthreads();
    int cb = 0;
#pragma unroll 2
    for (int kt = 0; kt < 24; ++kt) {
        if (kt < 23) { issueA(kt + 1); issueB(kt + 1, cb ^ 1); }
        compute(cb);
        if (kt < 23) writeA(cb ^ 1);
        __syncthreads();
        cb ^= 1;
    }
    const int gate = ntl >> 2;
    const float* bias = (gate == 0) ? ba : (gate == 1) ? br : br1;
    const int nnb = (ntl & 3) * 128 + wc * 64;
    const int rl = (lane >> 4) * 4, cl = lane & 15;
#pragma unroll
    for (int fm = 0; fm < 4; ++fm)
#pragma unroll
        for (int fn = 0; fn < 4; ++fn) {
            const int nn = nnb + fn * 16 + cl;
            const float b = bias[nn];
#pragma unroll
            for (int j = 0; j < 4; ++j) {
                const int row = m0 + wr * 64 + fm * 16 + rl + j;
                const size_t off = (size_t)row * 512 + nn;
                float v = acc[fm][fn][j] + b;
                float s = 1.0f / (1.0f + __expf(-v));
                if (gate == 0)      attf[off] = s;
                else if (gate == 1) hrw[off]  = f2bf(s * H[off]);
                else                pr1w[off] = f2bf(s * P[off]);
            }
        }
}

__global__ __launch_bounds__(256, 2)
void k2_small(const float* __restrict__ X, const float* __restrict__ H,
              const u16* __restrict__ B2, const float* __restrict__ bc,
              const u16* __restrict__ hrw, const u16* __restrict__ pr1w,
              float* outp)
{
    __shared__ u16 Ab[2][128 * 64];
    __shared__ u16 Bb[2][128 * 64];
    const int tid = threadIdx.x, lane = tid & 63, w = tid >> 6;
    const int wr = w >> 1, wc = w & 1;
    const int bid = blockIdx.x, xcd = bid & 7, idx = bid >> 3;
    const int panel = idx >> 2, ntl = idx & 3;
    const int m0 = (xcd * 64 + panel) * 128, n0 = ntl * 128;
    const int srow = w * 32 + (lane >> 3);
    const int scol = ((lane & 7) ^ (lane >> 3)) * 8;
    const int arow = tid >> 4, acol = (tid & 15) * 4;
    const int aswz = acol ^ ((arow & 7) << 3);
    f32x4 acc[4][4];
    const f32x4 vz = {0, 0, 0, 0};
#pragma unroll
    for (int i = 0; i < 4; ++i)
#pragma unroll
        for (int j = 0; j < 4; ++j) acc[i][j] = vz;
    f32x4 areg[8];
    auto issueA = [&](int kt, int nb) {
        if (kt >= 8) {
            const u16* src = (kt < 16) ? hrw : pr1w;
            const u16* gb = src + (size_t)(m0 + srow) * 512 + (kt & 7) * 64 + scol;
            u16* lb = &Ab[nb][(w * 32) * 64];
#pragma unroll
            for (int c = 0; c < 4; ++c)
                load_lds16(gb + (size_t)c * 8 * 512, lb + c * 8 * 64);
        } else {
            const float* base = X + (size_t)(m0 + arow) * 512 + (kt & 7) * 64 + acol;
#pragma unroll
            for (int rr = 0; rr < 8; ++rr)
                areg[rr] = *(const f32x4*)(base + (size_t)(rr * 16) * 512);
        }
    };
    auto writeA = [&](int kt, int nb) {
        if (kt < 8) {
#pragma unroll
            for (int rr = 0; rr < 8; ++rr) {
                uint2 q; q.x = f2bf2(areg[rr].x, areg[rr].y);
                q.y = f2bf2(areg[rr].z, areg[rr].w);
                *(uint2*)&Ab[nb][(arow + rr * 16) * 64 + aswz] = q;
            }
        }
    };
    auto issueB = [&](int kt, int nb) {
        const u16* gb = B2 + (size_t)(n0 + srow) * 1536 + kt * 64 + scol;
        u16* lb = &Bb[nb][(w * 32) * 64];
#pragma unroll
        for (int c = 0; c < 4; ++c)
            load_lds16(gb + (size_t)c * 8 * 1536, lb + c * 8 * 64);
    };
    auto compute = [&](int cb) {
        const int rsw = (lane & 7) << 3, rb = lane & 15, hi8 = (lane >> 4) * 8;
#pragma unroll
        for (int ks = 0; ks < 2; ++ks) {
            bf16x8 af[4], bfr[4];
            const int col = (ks * 32 + hi8) ^ rsw;
#pragma unroll
            for (int fm = 0; fm < 4; ++fm)
                af[fm] = *(const bf16x8*)&Ab[cb][(wr * 64 + fm * 16 + rb) * 64 + col];
#pragma unroll
            for (int fn = 0; fn < 4; ++fn)
                bfr[fn] = *(const bf16x8*)&Bb[cb][(wc * 64 + fn * 16 + rb) * 64 + col];
#pragma unroll
            for (int fm = 0; fm < 4; ++fm)
#pragma unroll
                for (int fn = 0; fn < 4; ++fn)
                    acc[fm][fn] = __builtin_amdgcn_mfma_f32_16x16x32_bf16(
                        af[fm], bfr[fn], acc[fm][fn], 0, 0, 0);
        }
    };
    issueA(0, 0); issueB(0, 0); writeA(0, 0);
    __syncthreads();
    int cb = 0;
#pragma unroll 2
    for (int kt = 0; kt < 24; ++kt) {
        if (kt < 23) { issueA(kt + 1, cb ^ 1); issueB(kt + 1, cb ^ 1); }
        compute(cb);
        if (kt < 23) writeA(kt + 1, cb ^ 1);
        __syncthreads();
        cb ^= 1;
    }
    const int nnb = n0 + wc * 64;
    const int rl = (lane >> 4) * 4, cl = lane & 15;
#pragma unroll
    for (int fm = 0; fm < 4; ++fm)
#pragma unroll
        for (int fn = 0; fn < 4; ++fn) {
            const int nn = nnb + fn * 16 + cl;
            const float b = bc[nn];
#pragma unroll
            for (int j = 0; j < 4; ++j) {
                const int row = m0 + wr * 64 + fm * 16 + rl + j;
                const size_t off = (size_t)row * 512 + nn;
                float v = acc[fm][fn][j] + b;
                float e = __expf(2.0f * v);
                float ct = 1.0f - 2.0f / (e + 1.0f);
                float a = outp[off];
                outp[off] = a * ct + (1.0f - a) * H[off];
            }
        }
}

extern "C" void kernel_launch(void* const* d_in, const int* in_sizes, int n_in,
                              void* d_out, int out_size, void* d_ws, size_t ws_size,
                              hipStream_t stream)
{
    const float* X   = (const float*)d_in[0];
    const float* H   = (const float*)d_in[1];
    const float* P   = (const float*)d_in[2];
    const float* wa  = (const float*)d_in[3];
    const float* ba  = (const float*)d_in[4];
    const float* wrg = (const float*)d_in[5];
    const float* br  = (const float*)d_in[6];
    const float* wr1 = (const float*)d_in[7];
    const float* br1 = (const float*)d_in[8];
    const float* wcc = (const float*)d_in[9];
    const float* bc  = (const float*)d_in[10];
    const float* ua  = (const float*)d_in[11];
    const float* ur  = (const float*)d_in[12];
    const float* ur1 = (const float*)d_in[13];
    const float* uc  = (const float*)d_in[14];
    const float* pa  = (const float*)d_in[15];
    const float* pr  = (const float*)d_in[16];
    const float* pr1 = (const float*)d_in[17];
    const float* pc  = (const float*)d_in[18];

    char* ws = (char*)d_ws;
    u16* B1   = (u16*)(ws);
    u16* B2   = (u16*)(ws + (size_t)4718592);
    u16* hrp  = (u16*)(ws + (size_t)6291456);
    u16* pr1p = (u16*)(ws + (size_t)73400320);
    u16* Xb   = (u16*)(ws + (size_t)140509184);
    u16* Hb   = (u16*)(ws + (size_t)207618048);
    u16* Pb   = (u16*)(ws + (size_t)274726912);
    u16* attb = (u16*)(ws + (size_t)341835776);
    float* out = (float*)d_out;

    const bool big3 = ws_size >= (size_t)408944640ULL;

    prep_weights<<<12288, 256, 0, stream>>>(wa, ua, pa, wrg, ur, pr, wr1, ur1, pr1,
                                            wcc, uc, pc, B1, B2);
    if (big3) {
        cast_inputs<<<3072, 256, 0, stream>>>(X, H, P, Xb, Hb, Pb);
        g128<1><<<6144, 256, 0, stream>>>(Xb, Hb, Pb, B1, ba, br, br1,
                                          Hb, Pb, attb, hrp, pr1p, out);
        g128<2><<<2048, 256, 0, stream>>>(Xb, hrp, pr1p, B2, bc, nullptr, nullptr,
                                          Hb, nullptr, attb, nullptr, nullptr, out);
    } else {
        k1_small<<<6144, 256, 0, stream>>>(X, H, P, B1, ba, br, br1, out, hrp, pr1p);
        k2_small<<<2048, 256, 0, stream>>>(X, H, B2, bc, hrp, pr1p, out);
    }
}